// Round 16
// baseline (332.685 us; speedup 1.0000x reference)
//
#include <hip/hip_runtime.h>

typedef unsigned short ushort_t;
typedef __attribute__((ext_vector_type(8))) short short8;
typedef __attribute__((ext_vector_type(4))) float f32x4;

__device__ inline float bflo(unsigned int u) { return __uint_as_float(u << 16); }
__device__ inline float bfhi(unsigned int u) { return __uint_as_float(u & 0xFFFF0000u); }
__device__ inline unsigned short f2bf(float f) {
    unsigned int u = __float_as_uint(f);
    return (unsigned short)((u + 0x7FFFu + ((u >> 16) & 1u)) >> 16);
}
__device__ inline unsigned int pk(float a, float b) {
    return (unsigned int)f2bf(a) | ((unsigned int)f2bf(b) << 16);
}

union U16B { uint4 u; short8 s; };

#define HB 1024   // hist blocks prepended to the gemm grid
#define SUBS 192  // fill sub-blocks per range (8 ranges)

// ============ fused: [blocks 0..HB) hist+rank] ∥ [blocks HB.. gemm Y=bf16(x@W1)] ============
__global__ __launch_bounds__(256) void gemm_hist(const float* __restrict__ x,
                                                 const float* __restrict__ W1,
                                                 ushort_t* __restrict__ Y, int n,
                                                 const int* __restrict__ dst,
                                                 int* __restrict__ deg,
                                                 int* __restrict__ rank, int E) {
    if (blockIdx.x < HB) {
        for (int e = blockIdx.x * 256 + threadIdx.x; e < E; e += HB * 256)
            rank[e] = atomicAdd(&deg[dst[e]], 1);
        return;
    }
    __shared__ ushort_t w1f[4][4][64][8];
    __shared__ ushort_t ybuf[64][72];
    for (int i = threadIdx.x; i < 8192; i += 256) {
        int j = i & 7, lane = (i >> 3) & 63, ct = (i >> 9) & 3, ks = (i >> 11) & 3;
        int k = ks * 32 + ((lane >> 4) << 3) + j;
        int c = ct * 16 + (lane & 15);
        w1f[ks][ct][lane][j] = f2bf(W1[k * 64 + c]);
    }
    __syncthreads();
    int w = threadIdx.x >> 6, lane = threadIdx.x & 63;
    int row0 = (blockIdx.x - HB) * 64;
    int arow = row0 + w * 16 + (lane & 15);
    if (arow >= n) arow = n - 1;
    const float* xr = x + (size_t)arow * 128;
    int k0base = (lane >> 4) << 3;

    f32x4 acc[4] = {{0,0,0,0},{0,0,0,0},{0,0,0,0},{0,0,0,0}};
#pragma unroll
    for (int ks = 0; ks < 4; ks++) {
        int k0 = ks * 32 + k0base;
        float4 aa = *(const float4*)(xr + k0);
        float4 ab = *(const float4*)(xr + k0 + 4);
        U16B af;
        af.u.x = pk(aa.x, aa.y);
        af.u.y = pk(aa.z, aa.w);
        af.u.z = pk(ab.x, ab.y);
        af.u.w = pk(ab.z, ab.w);
#pragma unroll
        for (int ct = 0; ct < 4; ct++) {
            short8 bf = *(const short8*)&w1f[ks][ct][lane][0];
            acc[ct] = __builtin_amdgcn_mfma_f32_16x16x32_bf16(af.s, bf, acc[ct], 0, 0, 0);
        }
    }
#pragma unroll
    for (int ct = 0; ct < 4; ct++)
#pragma unroll
        for (int r = 0; r < 4; r++)
            ybuf[w * 16 + ((lane >> 4) << 2) + r][ct * 16 + (lane & 15)] = f2bf(acc[ct][r]);
    __syncthreads();
    int row = threadIdx.x >> 2, seg = threadIdx.x & 3;
    if (row0 + row < n) {
        const uint4* p = (const uint4*)&ybuf[row][seg * 16];
        uint4 v0 = p[0], v1 = p[1];
        uint4* q = (uint4*)(Y + (size_t)(row0 + row) * 64 + seg * 16);
        q[0] = v0; q[1] = v1;
    }
}

// ============ merged scan + fill (one dispatch, flag-gated; all blocks co-resident) ============
__global__ __launch_bounds__(256) void scan_fill(const int* __restrict__ deg,
                                                 int* __restrict__ rowptr,
                                                 int* __restrict__ aggr,
                                                 int* __restrict__ flags,
                                                 int* __restrict__ flags2,
                                                 const int* __restrict__ src,
                                                 const int* __restrict__ dst,
                                                 const int* __restrict__ rank,
                                                 int* __restrict__ col,
                                                 int n, int E, int CE, int RB) {
    int t = threadIdx.x;
    if (blockIdx.x < 64) {
        __shared__ int sdata[256];
        __shared__ int sagg[64];
        int b = blockIdx.x;
        int base = b * 1024 + t * 4;
        int v[4]; int s = 0;
#pragma unroll
        for (int k = 0; k < 4; k++) { int i = base + k; v[k] = (i < n) ? deg[i] : 0; s += v[k]; }
        sdata[t] = s;
        __syncthreads();
        for (int off = 1; off < 256; off <<= 1) {
            int x = 0;
            if (t >= off) x = sdata[t - off];
            __syncthreads();
            if (t >= off) sdata[t] += x;
            __syncthreads();
        }
        int ex = sdata[t] - s;
        if (t == 255) {
            aggr[b] = sdata[255];
            __threadfence();
            atomicExch(&flags[b], 1);
        }
        if (t < 64) { while (atomicAdd(&flags[t], 0) == 0) {} }
        __syncthreads();
        if (t < 64) sagg[t] = aggr[t];
        __syncthreads();
        int bp = 0;
        for (int i = 0; i < b; i++) bp += sagg[i];
        int off = bp + ex;
#pragma unroll
        for (int k = 0; k < 4; k++) {
            int i = base + k;
            if (i < n) { rowptr[i] = off; off += v[k]; }
        }
        if (b == 63 && t == 255) rowptr[n] = bp + sdata[255];
        __syncthreads();
        __threadfence();
        if (t == 0) atomicExch(&flags2[b], 1);
    } else {
        if (t < 64) { while (atomicAdd(&flags2[t], 0) == 0) {} }
        __syncthreads();
        int fb = blockIdx.x - 64;
        int range = fb & 7;
        int sub = fb >> 3;
        int e0 = sub * CE;
        int e1 = min(e0 + CE, E);
        int lo = range * RB;
        int hi = lo + RB;
#pragma unroll 4
        for (int e = e0 + t; e < e1; e += 256) {
            int d = dst[e];
            if (d >= lo && d < hi) col[rowptr[d] + rank[e]] = src[e];
        }
    }
}

// ============ fused gather + 2-layer MLP via MFMA (+pool+finalize on last) ============
template <int HASNEXT>
__global__ __launch_bounds__(256) void gfuse(const ushort_t* __restrict__ Y,
                                             const int* __restrict__ rowptr,
                                             const int* __restrict__ col,
                                             const float* __restrict__ b1,
                                             const float* __restrict__ W2,
                                             const float* __restrict__ b2,
                                             const float* __restrict__ Wn,
                                             ushort_t* __restrict__ Yn,
                                             const int* __restrict__ batch,
                                             float* __restrict__ sums,
                                             int* __restrict__ done,
                                             const float* __restrict__ Wl,
                                             const float* __restrict__ bl,
                                             float* __restrict__ out, int G, int n) {
    __shared__ ushort_t w2f[2][4][64][8];
    __shared__ ushort_t wnf[HASNEXT ? 2 : 1][4][64][8];
    __shared__ ushort_t st[64][72];
    __shared__ float vbuf[HASNEXT ? 1 : 64][65];
    __shared__ float b1s[64], b2s[64];
    for (int i = threadIdx.x; i < 4096; i += 256) {
        int j = i & 7, lane = (i >> 3) & 63, ct = (i >> 9) & 3, ks = (i >> 11) & 1;
        int k = ks * 32 + ((lane >> 4) << 3) + j;
        int c = ct * 16 + (lane & 15);
        w2f[ks][ct][lane][j] = f2bf(W2[k * 64 + c]);
        if (HASNEXT) wnf[ks][ct][lane][j] = f2bf(Wn[k * 64 + c]);
    }
    if (threadIdx.x < 64) { b1s[threadIdx.x] = b1[threadIdx.x]; b2s[threadIdx.x] = b2[threadIdx.x]; }
    __syncthreads();

    int row0 = blockIdx.x * 64;

    // ---- gather phase: node = row0 + tid/4, dims [q*16, q*16+16) ----
    {
        int lr = threadIdx.x >> 2;
        int q  = threadIdx.x & 3;
        int gnode = row0 + lr;
        uint4 o0, o1;
        if (gnode < n) {
            const ushort_t* yb = Y + (size_t)gnode * 64 + q * 16;
            uint4 v0 = *(const uint4*)yb;
            uint4 v1 = *(const uint4*)(yb + 8);
            float ga[16];
            ga[0]=bflo(v0.x); ga[1]=bfhi(v0.x); ga[2]=bflo(v0.y); ga[3]=bfhi(v0.y);
            ga[4]=bflo(v0.z); ga[5]=bfhi(v0.z); ga[6]=bflo(v0.w); ga[7]=bfhi(v0.w);
            ga[8]=bflo(v1.x); ga[9]=bfhi(v1.x); ga[10]=bflo(v1.y); ga[11]=bfhi(v1.y);
            ga[12]=bflo(v1.z); ga[13]=bfhi(v1.z); ga[14]=bflo(v1.w); ga[15]=bfhi(v1.w);
            int e = rowptr[gnode], e1 = rowptr[gnode + 1];
            while (e + 1 < e1) {
                const ushort_t* p0 = Y + (size_t)col[e] * 64 + q * 16;
                const ushort_t* p1 = Y + (size_t)col[e + 1] * 64 + q * 16;
                uint4 a0 = *(const uint4*)p0, a1 = *(const uint4*)(p0 + 8);
                uint4 c0 = *(const uint4*)p1, c1 = *(const uint4*)(p1 + 8);
                ga[0]+=bflo(a0.x)+bflo(c0.x); ga[1]+=bfhi(a0.x)+bfhi(c0.x);
                ga[2]+=bflo(a0.y)+bflo(c0.y); ga[3]+=bfhi(a0.y)+bfhi(c0.y);
                ga[4]+=bflo(a0.z)+bflo(c0.z); ga[5]+=bfhi(a0.z)+bfhi(c0.z);
                ga[6]+=bflo(a0.w)+bflo(c0.w); ga[7]+=bfhi(a0.w)+bfhi(c0.w);
                ga[8]+=bflo(a1.x)+bflo(c1.x); ga[9]+=bfhi(a1.x)+bfhi(c1.x);
                ga[10]+=bflo(a1.y)+bflo(c1.y); ga[11]+=bfhi(a1.y)+bfhi(c1.y);
                ga[12]+=bflo(a1.z)+bflo(c1.z); ga[13]+=bfhi(a1.z)+bfhi(c1.z);
                ga[14]+=bflo(a1.w)+bflo(c1.w); ga[15]+=bfhi(a1.w)+bfhi(c1.w);
                e += 2;
            }
            if (e < e1) {
                const ushort_t* p0 = Y + (size_t)col[e] * 64 + q * 16;
                uint4 a0 = *(const uint4*)p0, a1 = *(const uint4*)(p0 + 8);
                ga[0]+=bflo(a0.x); ga[1]+=bfhi(a0.x); ga[2]+=bflo(a0.y); ga[3]+=bfhi(a0.y);
                ga[4]+=bflo(a0.z); ga[5]+=bfhi(a0.z); ga[6]+=bflo(a0.w); ga[7]+=bfhi(a0.w);
                ga[8]+=bflo(a1.x); ga[9]+=bfhi(a1.x); ga[10]+=bflo(a1.y); ga[11]+=bfhi(a1.y);
                ga[12]+=bflo(a1.z); ga[13]+=bfhi(a1.z); ga[14]+=bflo(a1.w); ga[15]+=bfhi(a1.w);
            }
            int d0 = q * 16;
#pragma unroll
            for (int j = 0; j < 16; j++) ga[j] = fmaxf(ga[j] + b1s[d0 + j], 0.0f);
            o0.x = pk(ga[0], ga[1]);  o0.y = pk(ga[2], ga[3]);
            o0.z = pk(ga[4], ga[5]);  o0.w = pk(ga[6], ga[7]);
            o1.x = pk(ga[8], ga[9]);  o1.y = pk(ga[10], ga[11]);
            o1.z = pk(ga[12], ga[13]); o1.w = pk(ga[14], ga[15]);
        } else {
            o0 = make_uint4(0, 0, 0, 0); o1 = o0;
        }
        *(uint4*)&st[lr][q * 16] = o0;
        *(uint4*)&st[lr][q * 16 + 8] = o1;
    }
    __syncthreads();

    // ---- GEMM1: acc = st @ W2 ----
    int w = threadIdx.x >> 6, lane = threadIdx.x & 63;
    int k0base = (lane >> 4) << 3;
    f32x4 acc[4] = {{0,0,0,0},{0,0,0,0},{0,0,0,0},{0,0,0,0}};
#pragma unroll
    for (int ks = 0; ks < 2; ks++) {
        short8 af = *(const short8*)&st[w * 16 + (lane & 15)][ks * 32 + k0base];
#pragma unroll
        for (int ct = 0; ct < 4; ct++) {
            short8 bf = *(const short8*)&w2f[ks][ct][lane][0];
            acc[ct] = __builtin_amdgcn_mfma_f32_16x16x32_bf16(af, bf, acc[ct], 0, 0, 0);
        }
    }
    __syncthreads();

    int colb = lane & 15;
    if (HASNEXT) {
#pragma unroll
        for (int ct = 0; ct < 4; ct++)
#pragma unroll
            for (int r = 0; r < 4; r++) {
                float v = fmaxf(acc[ct][r] + b2s[ct * 16 + colb], 0.0f);
                st[w * 16 + ((lane >> 4) << 2) + r][ct * 16 + colb] = f2bf(v);
            }
        __syncthreads();
        f32x4 acc2[4] = {{0,0,0,0},{0,0,0,0},{0,0,0,0},{0,0,0,0}};
#pragma unroll
        for (int ks = 0; ks < 2; ks++) {
            short8 af2 = *(const short8*)&st[w * 16 + (lane & 15)][ks * 32 + k0base];
#pragma unroll
            for (int ct = 0; ct < 4; ct++) {
                short8 bf = *(const short8*)&wnf[ks][ct][lane][0];
                acc2[ct] = __builtin_amdgcn_mfma_f32_16x16x32_bf16(af2, bf, acc2[ct], 0, 0, 0);
            }
        }
        __syncthreads();
#pragma unroll
        for (int ct = 0; ct < 4; ct++)
#pragma unroll
            for (int r = 0; r < 4; r++)
                st[w * 16 + ((lane >> 4) << 2) + r][ct * 16 + colb] = f2bf(acc2[ct][r]);
        __syncthreads();
        int row = threadIdx.x >> 2, seg = threadIdx.x & 3;
        if (row0 + row < n) {
            const uint4* p = (const uint4*)&st[row][seg * 16];
            uint4 v0 = p[0], v1 = p[1];
            uint4* qp = (uint4*)(Yn + (size_t)(row0 + row) * 64 + seg * 16);
            qp[0] = v0; qp[1] = v1;
        }
    } else {
        // pool reduce (sorted batch)
#pragma unroll
        for (int ct = 0; ct < 4; ct++)
#pragma unroll
            for (int r = 0; r < 4; r++) {
                float v = fmaxf(acc[ct][r] + b2s[ct * 16 + colb], 0.0f);
                vbuf[w * 16 + ((lane >> 4) << 2) + r][ct * 16 + colb] = v;
            }
        __syncthreads();
        int j  = threadIdx.x & 63;
        int i0 = (threadIdx.x >> 6) * 16;
        int cur = -1; float a = 0.0f;
        for (int i = i0; i < i0 + 16; i++) {
            int row = row0 + i;
            if (row >= n) break;
            int b = batch[row];
            if (b != cur) {
                if (cur >= 0) atomicAdd(&sums[cur * 64 + j], a);
                cur = b; a = 0.0f;
            }
            a += vbuf[i][j];
        }
        if (cur >= 0) atomicAdd(&sums[cur * 64 + j], a);

        // ---- finalize in last-finishing block (threadfence-reduction pattern) ----
        __threadfence();
        __syncthreads();
        __shared__ int amLast;
        if (threadIdx.x == 0)
            amLast = (atomicAdd(done, 1) == (int)gridDim.x - 1);
        __syncthreads();
        if (amLast) {
            __threadfence();  // acquire: see all blocks' sums
            __shared__ float gbuf[4][64];
            int jj = threadIdx.x & 63;
            int gq = threadIdx.x >> 6;   // 4 graphs at a time
            for (int g0 = 0; g0 < G; g0 += 4) {
                int g = g0 + gq;
                float v = 0.0f;
                if (g < G) {
                    int lo = 0, hi = n;
                    while (lo < hi) { int m = (lo + hi) >> 1; if (batch[m] < g) lo = m + 1; else hi = m; }
                    int lo2 = lo, hi2 = n;
                    while (lo2 < hi2) { int m = (lo2 + hi2) >> 1; if (batch[m] < g + 1) lo2 = m + 1; else hi2 = m; }
                    float c = (float)max(lo2 - lo, 1);
                    v = sums[g * 64 + jj] / c;
                    gbuf[gq][jj] = v;
                    out[G * 2 + g * 64 + jj] = v;
                }
                __syncthreads();
                if (g < G && jj < 2) {
                    float acch = bl[jj];
#pragma unroll
                    for (int k = 0; k < 64; k++) acch += gbuf[gq][k] * Wl[k * 2 + jj];
                    out[g * 2 + jj] = acch;
                }
                __syncthreads();
            }
        }
    }
}

extern "C" void kernel_launch(void* const* d_in, const int* in_sizes, int n_in,
                              void* d_out, int out_size, void* d_ws, size_t ws_size,
                              hipStream_t stream) {
    const float* x     = (const float*)d_in[0];
    const int*   ei    = (const int*)d_in[1];
    const int*   batch = (const int*)d_in[2];
    const float* W1_0 = (const float*)d_in[3];
    const float* b1_0 = (const float*)d_in[4];
    const float* W2_0 = (const float*)d_in[5];
    const float* b2_0 = (const float*)d_in[6];
    const float* W1_1 = (const float*)d_in[7];
    const float* b1_1 = (const float*)d_in[8];
    const float* W2_1 = (const float*)d_in[9];
    const float* b2_1 = (const float*)d_in[10];
    const float* W1_2 = (const float*)d_in[11];
    const float* b1_2 = (const float*)d_in[12];
    const float* W2_2 = (const float*)d_in[13];
    const float* b2_2 = (const float*)d_in[14];
    const float* Wl   = (const float*)d_in[15];
    const float* bl   = (const float*)d_in[16];

    const int N = in_sizes[0] / 128;
    const int E = in_sizes[1] / 2;
    const int G = out_size / 66;
    const int* src = ei;
    const int* dst = ei + E;
    float* out = (float*)d_out;

    // ---- workspace layout ----
    ushort_t* Y   = (ushort_t*)d_ws;                    // N*64 bf16
    ushort_t* Y2  = Y + (size_t)N * 64;                 // N*64 bf16 (ping-pong)
    float* sums   = (float*)(Y2 + (size_t)N * 64);      // G*64 f32
    int*   deg    = (int*)(sums + (size_t)G * 64);      // N
    int*   flags  = deg + N;                            // 64
    int*   flags2 = flags + 64;                         // 64
    int*   done   = flags2 + 64;                        // 64 (1 used)
    int*   rowptr = done + 64;                          // N+1
    int*   col    = rowptr + (N + 1);                   // E
    int*   rank   = col + E;                            // E
    int*   aggr   = rank + E;                           // 64

    // ---- zero sums | deg | flags | flags2 | done (contiguous) ----
    hipMemsetAsync(sums, 0, ((size_t)G * 64 + N + 192) * sizeof(int), stream);

    const int mblk = (N + 63) / 64;
    const int CE = (E + SUBS - 1) / SUBS;
    const int RB = (N + 7) / 8;

    // ---- CSR build + first GEMM ----
    gemm_hist<<<HB + mblk, 256, 0, stream>>>(x, W1_0, Y, N, dst, deg, rank, E);
    scan_fill<<<64 + 8 * SUBS, 256, 0, stream>>>(deg, rowptr, aggr, flags, flags2,
                                                 src, dst, rank, col, N, E, CE, RB);

    // ---- layers ----
    gfuse<1><<<mblk, 256, 0, stream>>>(Y, rowptr, col, b1_0, W2_0, b2_0, W1_1, Y2,
                                       nullptr, nullptr, nullptr, nullptr, nullptr, nullptr, G, N);
    gfuse<1><<<mblk, 256, 0, stream>>>(Y2, rowptr, col, b1_1, W2_1, b2_1, W1_2, Y,
                                       nullptr, nullptr, nullptr, nullptr, nullptr, nullptr, G, N);
    gfuse<0><<<mblk, 256, 0, stream>>>(Y, rowptr, col, b1_2, W2_2, b2_2, nullptr, nullptr,
                                       batch, sums, done, Wl, bl, out, G, N);
}

// Round 17
// 243.876 us; speedup vs baseline: 1.3642x; 1.3642x over previous
//
#include <hip/hip_runtime.h>

typedef unsigned short ushort_t;
typedef __attribute__((ext_vector_type(8))) short short8;
typedef __attribute__((ext_vector_type(4))) float f32x4;

__device__ inline float bflo(unsigned int u) { return __uint_as_float(u << 16); }
__device__ inline float bfhi(unsigned int u) { return __uint_as_float(u & 0xFFFF0000u); }
__device__ inline unsigned short f2bf(float f) {
    unsigned int u = __float_as_uint(f);
    return (unsigned short)((u + 0x7FFFu + ((u >> 16) & 1u)) >> 16);
}
__device__ inline unsigned int pk(float a, float b) {
    return (unsigned int)f2bf(a) | ((unsigned int)f2bf(b) << 16);
}

union U16B { uint4 u; short8 s; };

#define HB 1024   // hist blocks prepended to the gemm grid
#define SUBS 192  // fill sub-blocks per range (8 ranges)

// ============ fused: [blocks 0..HB) hist+rank] ∥ [blocks HB.. gemm Y=bf16(x@W1)] ============
__global__ __launch_bounds__(256) void gemm_hist(const float* __restrict__ x,
                                                 const float* __restrict__ W1,
                                                 ushort_t* __restrict__ Y, int n,
                                                 const int* __restrict__ dst,
                                                 int* __restrict__ deg,
                                                 int* __restrict__ rank, int E) {
    if (blockIdx.x < HB) {
        for (int e = blockIdx.x * 256 + threadIdx.x; e < E; e += HB * 256)
            rank[e] = atomicAdd(&deg[dst[e]], 1);
        return;
    }
    __shared__ ushort_t w1f[4][4][64][8];
    __shared__ ushort_t ybuf[64][72];
    for (int i = threadIdx.x; i < 8192; i += 256) {
        int j = i & 7, lane = (i >> 3) & 63, ct = (i >> 9) & 3, ks = (i >> 11) & 3;
        int k = ks * 32 + ((lane >> 4) << 3) + j;
        int c = ct * 16 + (lane & 15);
        w1f[ks][ct][lane][j] = f2bf(W1[k * 64 + c]);
    }
    __syncthreads();
    int w = threadIdx.x >> 6, lane = threadIdx.x & 63;
    int row0 = (blockIdx.x - HB) * 64;
    int arow = row0 + w * 16 + (lane & 15);
    if (arow >= n) arow = n - 1;
    const float* xr = x + (size_t)arow * 128;
    int k0base = (lane >> 4) << 3;

    f32x4 acc[4] = {{0,0,0,0},{0,0,0,0},{0,0,0,0},{0,0,0,0}};
#pragma unroll
    for (int ks = 0; ks < 4; ks++) {
        int k0 = ks * 32 + k0base;
        float4 aa = *(const float4*)(xr + k0);
        float4 ab = *(const float4*)(xr + k0 + 4);
        U16B af;
        af.u.x = pk(aa.x, aa.y);
        af.u.y = pk(aa.z, aa.w);
        af.u.z = pk(ab.x, ab.y);
        af.u.w = pk(ab.z, ab.w);
#pragma unroll
        for (int ct = 0; ct < 4; ct++) {
            short8 bf = *(const short8*)&w1f[ks][ct][lane][0];
            acc[ct] = __builtin_amdgcn_mfma_f32_16x16x32_bf16(af.s, bf, acc[ct], 0, 0, 0);
        }
    }
#pragma unroll
    for (int ct = 0; ct < 4; ct++)
#pragma unroll
        for (int r = 0; r < 4; r++)
            ybuf[w * 16 + ((lane >> 4) << 2) + r][ct * 16 + (lane & 15)] = f2bf(acc[ct][r]);
    __syncthreads();
    int row = threadIdx.x >> 2, seg = threadIdx.x & 3;
    if (row0 + row < n) {
        const uint4* p = (const uint4*)&ybuf[row][seg * 16];
        uint4 v0 = p[0], v1 = p[1];
        uint4* q = (uint4*)(Y + (size_t)(row0 + row) * 64 + seg * 16);
        q[0] = v0; q[1] = v1;
    }
}

// ============ merged scan + fill + cnt (one dispatch, flag-gated) ============
// blocks [0,64): scan deg -> rowptr.  blocks [64, 64+8*SUBS): col fill.
// block 64+8*SUBS: per-graph counts via parallel binary search (no waiting).
__global__ __launch_bounds__(256) void scan_fill(const int* __restrict__ deg,
                                                 int* __restrict__ rowptr,
                                                 int* __restrict__ aggr,
                                                 int* __restrict__ flags,
                                                 int* __restrict__ flags2,
                                                 const int* __restrict__ src,
                                                 const int* __restrict__ dst,
                                                 const int* __restrict__ rank,
                                                 int* __restrict__ col,
                                                 const int* __restrict__ batch,
                                                 float* __restrict__ cntf,
                                                 int n, int E, int CE, int RB, int G) {
    int t = threadIdx.x;
    if (blockIdx.x == 64 + 8 * SUBS) {
        // per-graph counts (independent of all other work)
        if (t < G) {
            int g = t;
            int lo = 0, hi = n;
            while (lo < hi) { int m = (lo + hi) >> 1; if (batch[m] < g) lo = m + 1; else hi = m; }
            int lo2 = lo, hi2 = n;
            while (lo2 < hi2) { int m = (lo2 + hi2) >> 1; if (batch[m] < g + 1) lo2 = m + 1; else hi2 = m; }
            cntf[g] = (float)max(lo2 - lo, 1);
        }
        return;
    }
    if (blockIdx.x < 64) {
        __shared__ int sdata[256];
        __shared__ int sagg[64];
        int b = blockIdx.x;
        int base = b * 1024 + t * 4;
        int v[4]; int s = 0;
#pragma unroll
        for (int k = 0; k < 4; k++) { int i = base + k; v[k] = (i < n) ? deg[i] : 0; s += v[k]; }
        sdata[t] = s;
        __syncthreads();
        for (int off = 1; off < 256; off <<= 1) {
            int x = 0;
            if (t >= off) x = sdata[t - off];
            __syncthreads();
            if (t >= off) sdata[t] += x;
            __syncthreads();
        }
        int ex = sdata[t] - s;
        if (t == 255) {
            aggr[b] = sdata[255];
            __threadfence();
            atomicExch(&flags[b], 1);
        }
        if (t < 64) { while (atomicAdd(&flags[t], 0) == 0) {} }
        __syncthreads();
        if (t < 64) sagg[t] = aggr[t];
        __syncthreads();
        int bp = 0;
        for (int i = 0; i < b; i++) bp += sagg[i];
        int off = bp + ex;
#pragma unroll
        for (int k = 0; k < 4; k++) {
            int i = base + k;
            if (i < n) { rowptr[i] = off; off += v[k]; }
        }
        if (b == 63 && t == 255) rowptr[n] = bp + sdata[255];
        __syncthreads();
        __threadfence();
        if (t == 0) atomicExch(&flags2[b], 1);
    } else {
        if (t < 64) { while (atomicAdd(&flags2[t], 0) == 0) {} }
        __syncthreads();
        int fb = blockIdx.x - 64;
        int range = fb & 7;
        int sub = fb >> 3;
        int e0 = sub * CE;
        int e1 = min(e0 + CE, E);
        int lo = range * RB;
        int hi = lo + RB;
#pragma unroll 4
        for (int e = e0 + t; e < e1; e += 256) {
            int d = dst[e];
            if (d >= lo && d < hi) col[rowptr[d] + rank[e]] = src[e];
        }
    }
}

// ============ fused gather + 2-layer MLP via MFMA (+pool+cheap finalize on last) ============
template <int HASNEXT>
__global__ __launch_bounds__(256) void gfuse(const ushort_t* __restrict__ Y,
                                             const int* __restrict__ rowptr,
                                             const int* __restrict__ col,
                                             const float* __restrict__ b1,
                                             const float* __restrict__ W2,
                                             const float* __restrict__ b2,
                                             const float* __restrict__ Wn,
                                             ushort_t* __restrict__ Yn,
                                             const int* __restrict__ batch,
                                             float* __restrict__ sums,
                                             int* __restrict__ done,
                                             const float* __restrict__ cntf,
                                             const float* __restrict__ Wl,
                                             const float* __restrict__ bl,
                                             float* __restrict__ out, int G, int n) {
    __shared__ ushort_t w2f[2][4][64][8];
    __shared__ ushort_t wnf[HASNEXT ? 2 : 1][4][64][8];
    __shared__ ushort_t st[64][72];
    __shared__ float vbuf[HASNEXT ? 1 : 64][65];
    __shared__ float b1s[64], b2s[64];
    for (int i = threadIdx.x; i < 4096; i += 256) {
        int j = i & 7, lane = (i >> 3) & 63, ct = (i >> 9) & 3, ks = (i >> 11) & 1;
        int k = ks * 32 + ((lane >> 4) << 3) + j;
        int c = ct * 16 + (lane & 15);
        w2f[ks][ct][lane][j] = f2bf(W2[k * 64 + c]);
        if (HASNEXT) wnf[ks][ct][lane][j] = f2bf(Wn[k * 64 + c]);
    }
    if (threadIdx.x < 64) { b1s[threadIdx.x] = b1[threadIdx.x]; b2s[threadIdx.x] = b2[threadIdx.x]; }
    __syncthreads();

    int row0 = blockIdx.x * 64;

    // ---- gather phase: node = row0 + tid/4, dims [q*16, q*16+16) ----
    {
        int lr = threadIdx.x >> 2;
        int q  = threadIdx.x & 3;
        int gnode = row0 + lr;
        uint4 o0, o1;
        if (gnode < n) {
            const ushort_t* yb = Y + (size_t)gnode * 64 + q * 16;
            uint4 v0 = *(const uint4*)yb;
            uint4 v1 = *(const uint4*)(yb + 8);
            float ga[16];
            ga[0]=bflo(v0.x); ga[1]=bfhi(v0.x); ga[2]=bflo(v0.y); ga[3]=bfhi(v0.y);
            ga[4]=bflo(v0.z); ga[5]=bfhi(v0.z); ga[6]=bflo(v0.w); ga[7]=bfhi(v0.w);
            ga[8]=bflo(v1.x); ga[9]=bfhi(v1.x); ga[10]=bflo(v1.y); ga[11]=bfhi(v1.y);
            ga[12]=bflo(v1.z); ga[13]=bfhi(v1.z); ga[14]=bflo(v1.w); ga[15]=bfhi(v1.w);
            int e = rowptr[gnode], e1 = rowptr[gnode + 1];
            while (e + 1 < e1) {
                const ushort_t* p0 = Y + (size_t)col[e] * 64 + q * 16;
                const ushort_t* p1 = Y + (size_t)col[e + 1] * 64 + q * 16;
                uint4 a0 = *(const uint4*)p0, a1 = *(const uint4*)(p0 + 8);
                uint4 c0 = *(const uint4*)p1, c1 = *(const uint4*)(p1 + 8);
                ga[0]+=bflo(a0.x)+bflo(c0.x); ga[1]+=bfhi(a0.x)+bfhi(c0.x);
                ga[2]+=bflo(a0.y)+bflo(c0.y); ga[3]+=bfhi(a0.y)+bfhi(c0.y);
                ga[4]+=bflo(a0.z)+bflo(c0.z); ga[5]+=bfhi(a0.z)+bfhi(c0.z);
                ga[6]+=bflo(a0.w)+bflo(c0.w); ga[7]+=bfhi(a0.w)+bfhi(c0.w);
                ga[8]+=bflo(a1.x)+bflo(c1.x); ga[9]+=bfhi(a1.x)+bfhi(c1.x);
                ga[10]+=bflo(a1.y)+bflo(c1.y); ga[11]+=bfhi(a1.y)+bfhi(c1.y);
                ga[12]+=bflo(a1.z)+bflo(c1.z); ga[13]+=bfhi(a1.z)+bfhi(c1.z);
                ga[14]+=bflo(a1.w)+bflo(c1.w); ga[15]+=bfhi(a1.w)+bfhi(c1.w);
                e += 2;
            }
            if (e < e1) {
                const ushort_t* p0 = Y + (size_t)col[e] * 64 + q * 16;
                uint4 a0 = *(const uint4*)p0, a1 = *(const uint4*)(p0 + 8);
                ga[0]+=bflo(a0.x); ga[1]+=bfhi(a0.x); ga[2]+=bflo(a0.y); ga[3]+=bfhi(a0.y);
                ga[4]+=bflo(a0.z); ga[5]+=bfhi(a0.z); ga[6]+=bflo(a0.w); ga[7]+=bfhi(a0.w);
                ga[8]+=bflo(a1.x); ga[9]+=bfhi(a1.x); ga[10]+=bflo(a1.y); ga[11]+=bfhi(a1.y);
                ga[12]+=bflo(a1.z); ga[13]+=bfhi(a1.z); ga[14]+=bflo(a1.w); ga[15]+=bfhi(a1.w);
            }
            int d0 = q * 16;
#pragma unroll
            for (int j = 0; j < 16; j++) ga[j] = fmaxf(ga[j] + b1s[d0 + j], 0.0f);
            o0.x = pk(ga[0], ga[1]);  o0.y = pk(ga[2], ga[3]);
            o0.z = pk(ga[4], ga[5]);  o0.w = pk(ga[6], ga[7]);
            o1.x = pk(ga[8], ga[9]);  o1.y = pk(ga[10], ga[11]);
            o1.z = pk(ga[12], ga[13]); o1.w = pk(ga[14], ga[15]);
        } else {
            o0 = make_uint4(0, 0, 0, 0); o1 = o0;
        }
        *(uint4*)&st[lr][q * 16] = o0;
        *(uint4*)&st[lr][q * 16 + 8] = o1;
    }
    __syncthreads();

    // ---- GEMM1: acc = st @ W2 ----
    int w = threadIdx.x >> 6, lane = threadIdx.x & 63;
    int k0base = (lane >> 4) << 3;
    f32x4 acc[4] = {{0,0,0,0},{0,0,0,0},{0,0,0,0},{0,0,0,0}};
#pragma unroll
    for (int ks = 0; ks < 2; ks++) {
        short8 af = *(const short8*)&st[w * 16 + (lane & 15)][ks * 32 + k0base];
#pragma unroll
        for (int ct = 0; ct < 4; ct++) {
            short8 bf = *(const short8*)&w2f[ks][ct][lane][0];
            acc[ct] = __builtin_amdgcn_mfma_f32_16x16x32_bf16(af, bf, acc[ct], 0, 0, 0);
        }
    }
    __syncthreads();

    int colb = lane & 15;
    if (HASNEXT) {
#pragma unroll
        for (int ct = 0; ct < 4; ct++)
#pragma unroll
            for (int r = 0; r < 4; r++) {
                float v = fmaxf(acc[ct][r] + b2s[ct * 16 + colb], 0.0f);
                st[w * 16 + ((lane >> 4) << 2) + r][ct * 16 + colb] = f2bf(v);
            }
        __syncthreads();
        f32x4 acc2[4] = {{0,0,0,0},{0,0,0,0},{0,0,0,0},{0,0,0,0}};
#pragma unroll
        for (int ks = 0; ks < 2; ks++) {
            short8 af2 = *(const short8*)&st[w * 16 + (lane & 15)][ks * 32 + k0base];
#pragma unroll
            for (int ct = 0; ct < 4; ct++) {
                short8 bf = *(const short8*)&wnf[ks][ct][lane][0];
                acc2[ct] = __builtin_amdgcn_mfma_f32_16x16x32_bf16(af2, bf, acc2[ct], 0, 0, 0);
            }
        }
        __syncthreads();
#pragma unroll
        for (int ct = 0; ct < 4; ct++)
#pragma unroll
            for (int r = 0; r < 4; r++)
                st[w * 16 + ((lane >> 4) << 2) + r][ct * 16 + colb] = f2bf(acc2[ct][r]);
        __syncthreads();
        int row = threadIdx.x >> 2, seg = threadIdx.x & 3;
        if (row0 + row < n) {
            const uint4* p = (const uint4*)&st[row][seg * 16];
            uint4 v0 = p[0], v1 = p[1];
            uint4* qp = (uint4*)(Yn + (size_t)(row0 + row) * 64 + seg * 16);
            qp[0] = v0; qp[1] = v1;
        }
    } else {
        // pool reduce (sorted batch)
#pragma unroll
        for (int ct = 0; ct < 4; ct++)
#pragma unroll
            for (int r = 0; r < 4; r++) {
                float v = fmaxf(acc[ct][r] + b2s[ct * 16 + colb], 0.0f);
                vbuf[w * 16 + ((lane >> 4) << 2) + r][ct * 16 + colb] = v;
            }
        __syncthreads();
        int j  = threadIdx.x & 63;
        int i0 = (threadIdx.x >> 6) * 16;
        int cur = -1; float a = 0.0f;
        for (int i = i0; i < i0 + 16; i++) {
            int row = row0 + i;
            if (row >= n) break;
            int b = batch[row];
            if (b != cur) {
                if (cur >= 0) atomicAdd(&sums[cur * 64 + j], a);
                cur = b; a = 0.0f;
            }
            a += vbuf[i][j];
        }
        if (cur >= 0) atomicAdd(&sums[cur * 64 + j], a);

        // ---- cheap finalize in last-finishing block (cnt precomputed) ----
        __threadfence();
        __syncthreads();
        __shared__ int amLast;
        if (threadIdx.x == 0)
            amLast = (atomicAdd(done, 1) == (int)gridDim.x - 1);
        __syncthreads();
        if (amLast) {
            __threadfence();
            __shared__ float gbuf[4][64];
            int jj = threadIdx.x & 63;
            int gq = threadIdx.x >> 6;
            for (int g0 = 0; g0 < G; g0 += 4) {
                int g = g0 + gq;
                if (g < G) {
                    float v = sums[g * 64 + jj] / cntf[g];
                    gbuf[gq][jj] = v;
                    out[G * 2 + g * 64 + jj] = v;
                }
                __syncthreads();
                if (g < G && jj < 2) {
                    float acch = bl[jj];
#pragma unroll
                    for (int k = 0; k < 64; k++) acch += gbuf[gq][k] * Wl[k * 2 + jj];
                    out[g * 2 + jj] = acch;
                }
                __syncthreads();
            }
        }
    }
}

extern "C" void kernel_launch(void* const* d_in, const int* in_sizes, int n_in,
                              void* d_out, int out_size, void* d_ws, size_t ws_size,
                              hipStream_t stream) {
    const float* x     = (const float*)d_in[0];
    const int*   ei    = (const int*)d_in[1];
    const int*   batch = (const int*)d_in[2];
    const float* W1_0 = (const float*)d_in[3];
    const float* b1_0 = (const float*)d_in[4];
    const float* W2_0 = (const float*)d_in[5];
    const float* b2_0 = (const float*)d_in[6];
    const float* W1_1 = (const float*)d_in[7];
    const float* b1_1 = (const float*)d_in[8];
    const float* W2_1 = (const float*)d_in[9];
    const float* b2_1 = (const float*)d_in[10];
    const float* W1_2 = (const float*)d_in[11];
    const float* b1_2 = (const float*)d_in[12];
    const float* W2_2 = (const float*)d_in[13];
    const float* b2_2 = (const float*)d_in[14];
    const float* Wl   = (const float*)d_in[15];
    const float* bl   = (const float*)d_in[16];

    const int N = in_sizes[0] / 128;
    const int E = in_sizes[1] / 2;
    const int G = out_size / 66;
    const int* src = ei;
    const int* dst = ei + E;
    float* out = (float*)d_out;

    // ---- workspace layout ----
    ushort_t* Y   = (ushort_t*)d_ws;                    // N*64 bf16
    ushort_t* Y2  = Y + (size_t)N * 64;                 // N*64 bf16 (ping-pong)
    float* sums   = (float*)(Y2 + (size_t)N * 64);      // G*64 f32
    int*   deg    = (int*)(sums + (size_t)G * 64);      // N
    int*   flags  = deg + N;                            // 64
    int*   flags2 = flags + 64;                         // 64
    int*   done   = flags2 + 64;                        // 64 (1 used)
    float* cntf   = (float*)(done + 64);                // G
    int*   rowptr = (int*)(cntf + G);                   // N+1
    int*   col    = rowptr + (N + 1);                   // E
    int*   rank   = col + E;                            // E
    int*   aggr   = rank + E;                           // 64

    // ---- zero sums | deg | flags | flags2 | done (contiguous) ----
    hipMemsetAsync(sums, 0, ((size_t)G * 64 + N + 192) * sizeof(int), stream);

    const int mblk = (N + 63) / 64;
    const int CE = (E + SUBS - 1) / SUBS;
    const int RB = (N + 7) / 8;

    // ---- CSR build + first GEMM ----
    gemm_hist<<<HB + mblk, 256, 0, stream>>>(x, W1_0, Y, N, dst, deg, rank, E);
    scan_fill<<<64 + 8 * SUBS + 1, 256, 0, stream>>>(deg, rowptr, aggr, flags, flags2,
                                                     src, dst, rank, col, batch, cntf,
                                                     N, E, CE, RB, G);

    // ---- layers ----
    gfuse<1><<<mblk, 256, 0, stream>>>(Y, rowptr, col, b1_0, W2_0, b2_0, W1_1, Y2,
                                       nullptr, nullptr, nullptr, nullptr, nullptr, nullptr, nullptr, G, N);
    gfuse<1><<<mblk, 256, 0, stream>>>(Y2, rowptr, col, b1_1, W2_1, b2_1, W1_2, Y,
                                       nullptr, nullptr, nullptr, nullptr, nullptr, nullptr, nullptr, G, N);
    gfuse<0><<<mblk, 256, 0, stream>>>(Y, rowptr, col, b1_2, W2_2, b2_2, nullptr, nullptr,
                                       batch, sums, done, cntf, Wl, bl, out, G, N);
}

// Round 18
// 167.620 us; speedup vs baseline: 1.9848x; 1.4549x over previous
//
#include <hip/hip_runtime.h>

typedef unsigned short ushort_t;
typedef __attribute__((ext_vector_type(8))) short short8;
typedef __attribute__((ext_vector_type(4))) float f32x4;

__device__ inline float bflo(unsigned int u) { return __uint_as_float(u << 16); }
__device__ inline float bfhi(unsigned int u) { return __uint_as_float(u & 0xFFFF0000u); }
__device__ inline unsigned short f2bf(float f) {
    unsigned int u = __float_as_uint(f);
    return (unsigned short)((u + 0x7FFFu + ((u >> 16) & 1u)) >> 16);
}
__device__ inline unsigned int pk(float a, float b) {
    return (unsigned int)f2bf(a) | ((unsigned int)f2bf(b) << 16);
}

union U16B { uint4 u; short8 s; };

#define HB 1024     // hist blocks prepended to the gemm grid
#define RANGES 4    // fill dst-ranges (col slice ~0.8 MB, L2-resident)
#define SUBS 192    // fill sub-blocks per range

// ============ fused: [blocks 0..HB) hist+rank] ∥ [blocks HB.. gemm Y=bf16(x@W1)] ============
__global__ __launch_bounds__(256) void gemm_hist(const float* __restrict__ x,
                                                 const float* __restrict__ W1,
                                                 ushort_t* __restrict__ Y, int n,
                                                 const int* __restrict__ dst,
                                                 int* __restrict__ deg,
                                                 int* __restrict__ rank, int E) {
    if (blockIdx.x < HB) {
        for (int e = blockIdx.x * 256 + threadIdx.x; e < E; e += HB * 256)
            rank[e] = atomicAdd(&deg[dst[e]], 1);
        return;
    }
    __shared__ ushort_t w1f[4][4][64][8];
    __shared__ ushort_t ybuf[64][72];
    for (int i = threadIdx.x; i < 8192; i += 256) {
        int j = i & 7, lane = (i >> 3) & 63, ct = (i >> 9) & 3, ks = (i >> 11) & 3;
        int k = ks * 32 + ((lane >> 4) << 3) + j;
        int c = ct * 16 + (lane & 15);
        w1f[ks][ct][lane][j] = f2bf(W1[k * 64 + c]);
    }
    __syncthreads();
    int w = threadIdx.x >> 6, lane = threadIdx.x & 63;
    int row0 = (blockIdx.x - HB) * 64;
    int arow = row0 + w * 16 + (lane & 15);
    if (arow >= n) arow = n - 1;
    const float* xr = x + (size_t)arow * 128;
    int k0base = (lane >> 4) << 3;

    f32x4 acc[4] = {{0,0,0,0},{0,0,0,0},{0,0,0,0},{0,0,0,0}};
#pragma unroll
    for (int ks = 0; ks < 4; ks++) {
        int k0 = ks * 32 + k0base;
        float4 aa = *(const float4*)(xr + k0);
        float4 ab = *(const float4*)(xr + k0 + 4);
        U16B af;
        af.u.x = pk(aa.x, aa.y);
        af.u.y = pk(aa.z, aa.w);
        af.u.z = pk(ab.x, ab.y);
        af.u.w = pk(ab.z, ab.w);
#pragma unroll
        for (int ct = 0; ct < 4; ct++) {
            short8 bf = *(const short8*)&w1f[ks][ct][lane][0];
            acc[ct] = __builtin_amdgcn_mfma_f32_16x16x32_bf16(af.s, bf, acc[ct], 0, 0, 0);
        }
    }
#pragma unroll
    for (int ct = 0; ct < 4; ct++)
#pragma unroll
        for (int r = 0; r < 4; r++)
            ybuf[w * 16 + ((lane >> 4) << 2) + r][ct * 16 + (lane & 15)] = f2bf(acc[ct][r]);
    __syncthreads();
    int row = threadIdx.x >> 2, seg = threadIdx.x & 3;
    if (row0 + row < n) {
        const uint4* p = (const uint4*)&ybuf[row][seg * 16];
        uint4 v0 = p[0], v1 = p[1];
        uint4* q = (uint4*)(Y + (size_t)(row0 + row) * 64 + seg * 16);
        q[0] = v0; q[1] = v1;
    }
}

// ============ merged scan + fill + cnt (one dispatch, flag-gated) ============
__global__ __launch_bounds__(256) void scan_fill(const int* __restrict__ deg,
                                                 int* __restrict__ rowptr,
                                                 int* __restrict__ aggr,
                                                 int* __restrict__ flags,
                                                 int* __restrict__ flags2,
                                                 const int* __restrict__ src,
                                                 const int* __restrict__ dst,
                                                 const int* __restrict__ rank,
                                                 int* __restrict__ col,
                                                 const int* __restrict__ batch,
                                                 float* __restrict__ cntf,
                                                 int n, int E, int CE, int RB, int G) {
    int t = threadIdx.x;
    if (blockIdx.x == 64 + RANGES * SUBS) {
        // per-graph counts (independent of all other work)
        if (t < G) {
            int g = t;
            int lo = 0, hi = n;
            while (lo < hi) { int m = (lo + hi) >> 1; if (batch[m] < g) lo = m + 1; else hi = m; }
            int lo2 = lo, hi2 = n;
            while (lo2 < hi2) { int m = (lo2 + hi2) >> 1; if (batch[m] < g + 1) lo2 = m + 1; else hi2 = m; }
            cntf[g] = (float)max(lo2 - lo, 1);
        }
        return;
    }
    if (blockIdx.x < 64) {
        __shared__ int sdata[256];
        __shared__ int sagg[64];
        int b = blockIdx.x;
        int base = b * 1024 + t * 4;
        int v[4]; int s = 0;
#pragma unroll
        for (int k = 0; k < 4; k++) { int i = base + k; v[k] = (i < n) ? deg[i] : 0; s += v[k]; }
        sdata[t] = s;
        __syncthreads();
        for (int off = 1; off < 256; off <<= 1) {
            int x = 0;
            if (t >= off) x = sdata[t - off];
            __syncthreads();
            if (t >= off) sdata[t] += x;
            __syncthreads();
        }
        int ex = sdata[t] - s;
        if (t == 255) {
            aggr[b] = sdata[255];
            __threadfence();
            atomicExch(&flags[b], 1);
        }
        if (t < 64) { while (atomicAdd(&flags[t], 0) == 0) {} }
        __syncthreads();
        if (t < 64) sagg[t] = aggr[t];
        __syncthreads();
        int bp = 0;
        for (int i = 0; i < b; i++) bp += sagg[i];
        int off = bp + ex;
#pragma unroll
        for (int k = 0; k < 4; k++) {
            int i = base + k;
            if (i < n) { rowptr[i] = off; off += v[k]; }
        }
        if (b == 63 && t == 255) rowptr[n] = bp + sdata[255];
        __syncthreads();
        __threadfence();
        if (t == 0) atomicExch(&flags2[b], 1);
    } else {
        if (t < 64) { while (atomicAdd(&flags2[t], 0) == 0) {} }
        __syncthreads();
        int fb = blockIdx.x - 64;
        int range = fb & (RANGES - 1);
        int sub = fb >> 2;                  // RANGES = 4
        int e0 = sub * CE;
        int e1 = min(e0 + CE, E);
        int lo = range * RB;
        int hi = lo + RB;
#pragma unroll 4
        for (int e = e0 + t; e < e1; e += 256) {
            int d = dst[e];
            if (d >= lo && d < hi) col[rowptr[d] + rank[e]] = src[e];
        }
    }
}

// ============ fused gather + 2-layer MLP via MFMA (+pool on last) ============
template <int HASNEXT>
__global__ __launch_bounds__(256) void gfuse(const ushort_t* __restrict__ Y,
                                             const int* __restrict__ rowptr,
                                             const int* __restrict__ col,
                                             const float* __restrict__ b1,
                                             const float* __restrict__ W2,
                                             const float* __restrict__ b2,
                                             const float* __restrict__ Wn,
                                             ushort_t* __restrict__ Yn,
                                             const int* __restrict__ batch,
                                             float* __restrict__ sums, int n) {
    __shared__ ushort_t w2f[2][4][64][8];
    __shared__ ushort_t wnf[HASNEXT ? 2 : 1][4][64][8];
    __shared__ ushort_t st[64][72];
    __shared__ float vbuf[HASNEXT ? 1 : 64][65];
    __shared__ float b1s[64], b2s[64];
    for (int i = threadIdx.x; i < 4096; i += 256) {
        int j = i & 7, lane = (i >> 3) & 63, ct = (i >> 9) & 3, ks = (i >> 11) & 1;
        int k = ks * 32 + ((lane >> 4) << 3) + j;
        int c = ct * 16 + (lane & 15);
        w2f[ks][ct][lane][j] = f2bf(W2[k * 64 + c]);
        if (HASNEXT) wnf[ks][ct][lane][j] = f2bf(Wn[k * 64 + c]);
    }
    if (threadIdx.x < 64) { b1s[threadIdx.x] = b1[threadIdx.x]; b2s[threadIdx.x] = b2[threadIdx.x]; }
    __syncthreads();

    int row0 = blockIdx.x * 64;

    // ---- gather phase: node = row0 + tid/4, dims [q*16, q*16+16) ----
    {
        int lr = threadIdx.x >> 2;
        int q  = threadIdx.x & 3;
        int gnode = row0 + lr;
        uint4 o0, o1;
        if (gnode < n) {
            const ushort_t* yb = Y + (size_t)gnode * 64 + q * 16;
            uint4 v0 = *(const uint4*)yb;
            uint4 v1 = *(const uint4*)(yb + 8);
            float ga[16];
            ga[0]=bflo(v0.x); ga[1]=bfhi(v0.x); ga[2]=bflo(v0.y); ga[3]=bfhi(v0.y);
            ga[4]=bflo(v0.z); ga[5]=bfhi(v0.z); ga[6]=bflo(v0.w); ga[7]=bfhi(v0.w);
            ga[8]=bflo(v1.x); ga[9]=bfhi(v1.x); ga[10]=bflo(v1.y); ga[11]=bfhi(v1.y);
            ga[12]=bflo(v1.z); ga[13]=bfhi(v1.z); ga[14]=bflo(v1.w); ga[15]=bfhi(v1.w);
            int e = rowptr[gnode], e1 = rowptr[gnode + 1];
            while (e + 1 < e1) {
                const ushort_t* p0 = Y + (size_t)col[e] * 64 + q * 16;
                const ushort_t* p1 = Y + (size_t)col[e + 1] * 64 + q * 16;
                uint4 a0 = *(const uint4*)p0, a1 = *(const uint4*)(p0 + 8);
                uint4 c0 = *(const uint4*)p1, c1 = *(const uint4*)(p1 + 8);
                ga[0]+=bflo(a0.x)+bflo(c0.x); ga[1]+=bfhi(a0.x)+bfhi(c0.x);
                ga[2]+=bflo(a0.y)+bflo(c0.y); ga[3]+=bfhi(a0.y)+bfhi(c0.y);
                ga[4]+=bflo(a0.z)+bflo(c0.z); ga[5]+=bfhi(a0.z)+bfhi(c0.z);
                ga[6]+=bflo(a0.w)+bflo(c0.w); ga[7]+=bfhi(a0.w)+bfhi(c0.w);
                ga[8]+=bflo(a1.x)+bflo(c1.x); ga[9]+=bfhi(a1.x)+bfhi(c1.x);
                ga[10]+=bflo(a1.y)+bflo(c1.y); ga[11]+=bfhi(a1.y)+bfhi(c1.y);
                ga[12]+=bflo(a1.z)+bflo(c1.z); ga[13]+=bfhi(a1.z)+bfhi(c1.z);
                ga[14]+=bflo(a1.w)+bflo(c1.w); ga[15]+=bfhi(a1.w)+bfhi(c1.w);
                e += 2;
            }
            if (e < e1) {
                const ushort_t* p0 = Y + (size_t)col[e] * 64 + q * 16;
                uint4 a0 = *(const uint4*)p0, a1 = *(const uint4*)(p0 + 8);
                ga[0]+=bflo(a0.x); ga[1]+=bfhi(a0.x); ga[2]+=bflo(a0.y); ga[3]+=bfhi(a0.y);
                ga[4]+=bflo(a0.z); ga[5]+=bfhi(a0.z); ga[6]+=bflo(a0.w); ga[7]+=bfhi(a0.w);
                ga[8]+=bflo(a1.x); ga[9]+=bfhi(a1.x); ga[10]+=bflo(a1.y); ga[11]+=bfhi(a1.y);
                ga[12]+=bflo(a1.z); ga[13]+=bfhi(a1.z); ga[14]+=bflo(a1.w); ga[15]+=bfhi(a1.w);
            }
            int d0 = q * 16;
#pragma unroll
            for (int j = 0; j < 16; j++) ga[j] = fmaxf(ga[j] + b1s[d0 + j], 0.0f);
            o0.x = pk(ga[0], ga[1]);  o0.y = pk(ga[2], ga[3]);
            o0.z = pk(ga[4], ga[5]);  o0.w = pk(ga[6], ga[7]);
            o1.x = pk(ga[8], ga[9]);  o1.y = pk(ga[10], ga[11]);
            o1.z = pk(ga[12], ga[13]); o1.w = pk(ga[14], ga[15]);
        } else {
            o0 = make_uint4(0, 0, 0, 0); o1 = o0;
        }
        *(uint4*)&st[lr][q * 16] = o0;
        *(uint4*)&st[lr][q * 16 + 8] = o1;
    }
    __syncthreads();

    // ---- GEMM1: acc = st @ W2 ----
    int w = threadIdx.x >> 6, lane = threadIdx.x & 63;
    int k0base = (lane >> 4) << 3;
    f32x4 acc[4] = {{0,0,0,0},{0,0,0,0},{0,0,0,0},{0,0,0,0}};
#pragma unroll
    for (int ks = 0; ks < 2; ks++) {
        short8 af = *(const short8*)&st[w * 16 + (lane & 15)][ks * 32 + k0base];
#pragma unroll
        for (int ct = 0; ct < 4; ct++) {
            short8 bf = *(const short8*)&w2f[ks][ct][lane][0];
            acc[ct] = __builtin_amdgcn_mfma_f32_16x16x32_bf16(af, bf, acc[ct], 0, 0, 0);
        }
    }
    __syncthreads();

    int colb = lane & 15;
    if (HASNEXT) {
#pragma unroll
        for (int ct = 0; ct < 4; ct++)
#pragma unroll
            for (int r = 0; r < 4; r++) {
                float v = fmaxf(acc[ct][r] + b2s[ct * 16 + colb], 0.0f);
                st[w * 16 + ((lane >> 4) << 2) + r][ct * 16 + colb] = f2bf(v);
            }
        __syncthreads();
        f32x4 acc2[4] = {{0,0,0,0},{0,0,0,0},{0,0,0,0},{0,0,0,0}};
#pragma unroll
        for (int ks = 0; ks < 2; ks++) {
            short8 af2 = *(const short8*)&st[w * 16 + (lane & 15)][ks * 32 + k0base];
#pragma unroll
            for (int ct = 0; ct < 4; ct++) {
                short8 bf = *(const short8*)&wnf[ks][ct][lane][0];
                acc2[ct] = __builtin_amdgcn_mfma_f32_16x16x32_bf16(af2, bf, acc2[ct], 0, 0, 0);
            }
        }
        __syncthreads();
#pragma unroll
        for (int ct = 0; ct < 4; ct++)
#pragma unroll
            for (int r = 0; r < 4; r++)
                st[w * 16 + ((lane >> 4) << 2) + r][ct * 16 + colb] = f2bf(acc2[ct][r]);
        __syncthreads();
        int row = threadIdx.x >> 2, seg = threadIdx.x & 3;
        if (row0 + row < n) {
            const uint4* p = (const uint4*)&st[row][seg * 16];
            uint4 v0 = p[0], v1 = p[1];
            uint4* qp = (uint4*)(Yn + (size_t)(row0 + row) * 64 + seg * 16);
            qp[0] = v0; qp[1] = v1;
        }
    } else {
        // pool reduce (sorted batch)
#pragma unroll
        for (int ct = 0; ct < 4; ct++)
#pragma unroll
            for (int r = 0; r < 4; r++) {
                float v = fmaxf(acc[ct][r] + b2s[ct * 16 + colb], 0.0f);
                vbuf[w * 16 + ((lane >> 4) << 2) + r][ct * 16 + colb] = v;
            }
        __syncthreads();
        int j  = threadIdx.x & 63;
        int i0 = (threadIdx.x >> 6) * 16;
        int cur = -1; float a = 0.0f;
        for (int i = i0; i < i0 + 16; i++) {
            int row = row0 + i;
            if (row >= n) break;
            int b = batch[row];
            if (b != cur) {
                if (cur >= 0) atomicAdd(&sums[cur * 64 + j], a);
                cur = b; a = 0.0f;
            }
            a += vbuf[i][j];
        }
        if (cur >= 0) atomicAdd(&sums[cur * 64 + j], a);
    }
}

// ============ finalize: uses precomputed cntf ============
__global__ __launch_bounds__(64) void finalize_kernel(const float* __restrict__ sums,
                                                      const float* __restrict__ cntf,
                                                      const float* __restrict__ Wl,
                                                      const float* __restrict__ bl,
                                                      float* __restrict__ out, int G) {
    int g = blockIdx.x;
    int j = threadIdx.x;
    __shared__ float gs[64];
    float v = sums[g * 64 + j] / cntf[g];
    gs[j] = v;
    out[G * 2 + g * 64 + j] = v;
    __syncthreads();
    if (j < 2) {
        float acc = bl[j];
#pragma unroll
        for (int k = 0; k < 64; k++) acc += gs[k] * Wl[k * 2 + j];
        out[g * 2 + j] = acc;
    }
}

extern "C" void kernel_launch(void* const* d_in, const int* in_sizes, int n_in,
                              void* d_out, int out_size, void* d_ws, size_t ws_size,
                              hipStream_t stream) {
    const float* x     = (const float*)d_in[0];
    const int*   ei    = (const int*)d_in[1];
    const int*   batch = (const int*)d_in[2];
    const float* W1_0 = (const float*)d_in[3];
    const float* b1_0 = (const float*)d_in[4];
    const float* W2_0 = (const float*)d_in[5];
    const float* b2_0 = (const float*)d_in[6];
    const float* W1_1 = (const float*)d_in[7];
    const float* b1_1 = (const float*)d_in[8];
    const float* W2_1 = (const float*)d_in[9];
    const float* b2_1 = (const float*)d_in[10];
    const float* W1_2 = (const float*)d_in[11];
    const float* b1_2 = (const float*)d_in[12];
    const float* W2_2 = (const float*)d_in[13];
    const float* b2_2 = (const float*)d_in[14];
    const float* Wl   = (const float*)d_in[15];
    const float* bl   = (const float*)d_in[16];

    const int N = in_sizes[0] / 128;
    const int E = in_sizes[1] / 2;
    const int G = out_size / 66;
    const int* src = ei;
    const int* dst = ei + E;
    float* out = (float*)d_out;

    // ---- workspace layout ----
    ushort_t* Y   = (ushort_t*)d_ws;                    // N*64 bf16
    ushort_t* Y2  = Y + (size_t)N * 64;                 // N*64 bf16 (ping-pong)
    float* sums   = (float*)(Y2 + (size_t)N * 64);      // G*64 f32
    int*   deg    = (int*)(sums + (size_t)G * 64);      // N
    int*   flags  = deg + N;                            // 64
    int*   flags2 = flags + 64;                         // 64
    float* cntf   = (float*)(flags2 + 64);              // G (zeroed -> overwritten)
    int*   rowptr = (int*)(cntf + G);                   // N+1
    int*   col    = rowptr + (N + 1);                   // E
    int*   rank   = col + E;                            // E
    int*   aggr   = rank + E;                           // 64

    // ---- zero sums | deg | flags | flags2 (contiguous) ----
    hipMemsetAsync(sums, 0, ((size_t)G * 64 + N + 128) * sizeof(int), stream);

    const int mblk = (N + 63) / 64;
    const int CE = (E + SUBS - 1) / SUBS;
    const int RB = (N + RANGES - 1) / RANGES;

    // ---- CSR build + first GEMM ----
    gemm_hist<<<HB + mblk, 256, 0, stream>>>(x, W1_0, Y, N, dst, deg, rank, E);
    scan_fill<<<64 + RANGES * SUBS + 1, 256, 0, stream>>>(deg, rowptr, aggr, flags, flags2,
                                                          src, dst, rank, col, batch, cntf,
                                                          N, E, CE, RB, G);

    // ---- layers ----
    gfuse<1><<<mblk, 256, 0, stream>>>(Y, rowptr, col, b1_0, W2_0, b2_0, W1_1, Y2, nullptr, nullptr, N);
    gfuse<1><<<mblk, 256, 0, stream>>>(Y2, rowptr, col, b1_1, W2_1, b2_1, W1_2, Y, nullptr, nullptr, N);
    gfuse<0><<<mblk, 256, 0, stream>>>(Y, rowptr, col, b1_2, W2_2, b2_2, nullptr, nullptr, batch, sums, N);
    // ---- head ----
    finalize_kernel<<<G, 64, 0, stream>>>(sums, cntf, Wl, bl, out, G);
}

// Round 19
// 161.120 us; speedup vs baseline: 2.0648x; 1.0403x over previous
//
#include <hip/hip_runtime.h>

typedef unsigned short ushort_t;
typedef __attribute__((ext_vector_type(8))) short short8;
typedef __attribute__((ext_vector_type(4))) float f32x4;

__device__ inline float bflo(unsigned int u) { return __uint_as_float(u << 16); }
__device__ inline float bfhi(unsigned int u) { return __uint_as_float(u & 0xFFFF0000u); }
__device__ inline unsigned short f2bf(float f) {
    unsigned int u = __float_as_uint(f);
    return (unsigned short)((u + 0x7FFFu + ((u >> 16) & 1u)) >> 16);
}
__device__ inline unsigned int pk(float a, float b) {
    return (unsigned int)f2bf(a) | ((unsigned int)f2bf(b) << 16);
}

union U16B { uint4 u; short8 s; };

#define HB 512      // hist blocks prepended to the gemm grid (512 measured faster than 1024)
#define RANGES 4    // fill dst-ranges (col slice ~0.8 MB, L2-resident)
#define SUBS 192    // fill sub-blocks per range

// ============ fused: [blocks 0..HB) hist+rank] ∥ [blocks HB.. gemm Y=bf16(x@W1)] ============
__global__ __launch_bounds__(256) void gemm_hist(const float* __restrict__ x,
                                                 const float* __restrict__ W1,
                                                 ushort_t* __restrict__ Y, int n,
                                                 const int* __restrict__ dst,
                                                 int* __restrict__ deg,
                                                 int* __restrict__ rank, int E) {
    if (blockIdx.x < HB) {
        for (int e = blockIdx.x * 256 + threadIdx.x; e < E; e += HB * 256)
            rank[e] = atomicAdd(&deg[dst[e]], 1);
        return;
    }
    __shared__ ushort_t w1f[4][4][64][8];
    __shared__ ushort_t ybuf[64][72];
    for (int i = threadIdx.x; i < 8192; i += 256) {
        int j = i & 7, lane = (i >> 3) & 63, ct = (i >> 9) & 3, ks = (i >> 11) & 3;
        int k = ks * 32 + ((lane >> 4) << 3) + j;
        int c = ct * 16 + (lane & 15);
        w1f[ks][ct][lane][j] = f2bf(W1[k * 64 + c]);
    }
    __syncthreads();
    int w = threadIdx.x >> 6, lane = threadIdx.x & 63;
    int row0 = (blockIdx.x - HB) * 64;
    int arow = row0 + w * 16 + (lane & 15);
    if (arow >= n) arow = n - 1;
    const float* xr = x + (size_t)arow * 128;
    int k0base = (lane >> 4) << 3;

    f32x4 acc[4] = {{0,0,0,0},{0,0,0,0},{0,0,0,0},{0,0,0,0}};
#pragma unroll
    for (int ks = 0; ks < 4; ks++) {
        int k0 = ks * 32 + k0base;
        float4 aa = *(const float4*)(xr + k0);
        float4 ab = *(const float4*)(xr + k0 + 4);
        U16B af;
        af.u.x = pk(aa.x, aa.y);
        af.u.y = pk(aa.z, aa.w);
        af.u.z = pk(ab.x, ab.y);
        af.u.w = pk(ab.z, ab.w);
#pragma unroll
        for (int ct = 0; ct < 4; ct++) {
            short8 bf = *(const short8*)&w1f[ks][ct][lane][0];
            acc[ct] = __builtin_amdgcn_mfma_f32_16x16x32_bf16(af.s, bf, acc[ct], 0, 0, 0);
        }
    }
#pragma unroll
    for (int ct = 0; ct < 4; ct++)
#pragma unroll
        for (int r = 0; r < 4; r++)
            ybuf[w * 16 + ((lane >> 4) << 2) + r][ct * 16 + (lane & 15)] = f2bf(acc[ct][r]);
    __syncthreads();
    int row = threadIdx.x >> 2, seg = threadIdx.x & 3;
    if (row0 + row < n) {
        const uint4* p = (const uint4*)&ybuf[row][seg * 16];
        uint4 v0 = p[0], v1 = p[1];
        uint4* q = (uint4*)(Y + (size_t)(row0 + row) * 64 + seg * 16);
        q[0] = v0; q[1] = v1;
    }
}

// ============ merged scan + fill + cnt (one dispatch, flag-gated) ============
__global__ __launch_bounds__(256) void scan_fill(const int* __restrict__ deg,
                                                 int* __restrict__ rowptr,
                                                 int* __restrict__ aggr,
                                                 int* __restrict__ flags,
                                                 int* __restrict__ flags2,
                                                 const int* __restrict__ src,
                                                 const int* __restrict__ dst,
                                                 const int* __restrict__ rank,
                                                 int* __restrict__ col,
                                                 const int* __restrict__ batch,
                                                 float* __restrict__ cntf,
                                                 int n, int E, int CE, int RB, int G) {
    int t = threadIdx.x;
    if (blockIdx.x == 64 + RANGES * SUBS) {
        if (t < G) {
            int g = t;
            int lo = 0, hi = n;
            while (lo < hi) { int m = (lo + hi) >> 1; if (batch[m] < g) lo = m + 1; else hi = m; }
            int lo2 = lo, hi2 = n;
            while (lo2 < hi2) { int m = (lo2 + hi2) >> 1; if (batch[m] < g + 1) lo2 = m + 1; else hi2 = m; }
            cntf[g] = (float)max(lo2 - lo, 1);
        }
        return;
    }
    if (blockIdx.x < 64) {
        __shared__ int sdata[256];
        __shared__ int sagg[64];
        int b = blockIdx.x;
        int base = b * 1024 + t * 4;
        int v[4]; int s = 0;
#pragma unroll
        for (int k = 0; k < 4; k++) { int i = base + k; v[k] = (i < n) ? deg[i] : 0; s += v[k]; }
        sdata[t] = s;
        __syncthreads();
        for (int off = 1; off < 256; off <<= 1) {
            int x = 0;
            if (t >= off) x = sdata[t - off];
            __syncthreads();
            if (t >= off) sdata[t] += x;
            __syncthreads();
        }
        int ex = sdata[t] - s;
        if (t == 255) {
            aggr[b] = sdata[255];
            __threadfence();
            atomicExch(&flags[b], 1);
        }
        if (t < 64) { while (atomicAdd(&flags[t], 0) == 0) {} }
        __syncthreads();
        if (t < 64) sagg[t] = aggr[t];
        __syncthreads();
        int bp = 0;
        for (int i = 0; i < b; i++) bp += sagg[i];
        int off = bp + ex;
#pragma unroll
        for (int k = 0; k < 4; k++) {
            int i = base + k;
            if (i < n) { rowptr[i] = off; off += v[k]; }
        }
        if (b == 63 && t == 255) rowptr[n] = bp + sdata[255];
        __syncthreads();
        __threadfence();
        if (t == 0) atomicExch(&flags2[b], 1);
    } else {
        if (t < 64) { while (atomicAdd(&flags2[t], 0) == 0) {} }
        __syncthreads();
        int fb = blockIdx.x - 64;
        int range = fb & (RANGES - 1);
        int sub = fb >> 2;
        int e0 = sub * CE;
        int e1 = min(e0 + CE, E);
        int lo = range * RB;
        int hi = lo + RB;
#pragma unroll 4
        for (int e = e0 + t; e < e1; e += 256) {
            int d = dst[e];
            if (d >= lo && d < hi) col[rowptr[d] + rank[e]] = src[e];
        }
    }
}

// ============ fused gather + 2-layer MLP via MFMA (+pool on last) ============
template <int HASNEXT>
__global__ __launch_bounds__(256) void gfuse(const ushort_t* __restrict__ Y,
                                             const int* __restrict__ rowptr,
                                             const int* __restrict__ col,
                                             const float* __restrict__ b1,
                                             const float* __restrict__ W2,
                                             const float* __restrict__ b2,
                                             const float* __restrict__ Wn,
                                             ushort_t* __restrict__ Yn,
                                             const int* __restrict__ batch,
                                             float* __restrict__ sums, int n) {
    __shared__ ushort_t w2f[2][4][64][8];
    __shared__ ushort_t wnf[HASNEXT ? 2 : 1][4][64][8];
    __shared__ ushort_t st[64][72];
    __shared__ float vbuf[HASNEXT ? 1 : 64][65];
    __shared__ float b1s[64], b2s[64];
    for (int i = threadIdx.x; i < 4096; i += 256) {
        int j = i & 7, lane = (i >> 3) & 63, ct = (i >> 9) & 3, ks = (i >> 11) & 1;
        int k = ks * 32 + ((lane >> 4) << 3) + j;
        int c = ct * 16 + (lane & 15);
        w2f[ks][ct][lane][j] = f2bf(W2[k * 64 + c]);
        if (HASNEXT) wnf[ks][ct][lane][j] = f2bf(Wn[k * 64 + c]);
    }
    if (threadIdx.x < 64) { b1s[threadIdx.x] = b1[threadIdx.x]; b2s[threadIdx.x] = b2[threadIdx.x]; }
    __syncthreads();

    int row0 = blockIdx.x * 64;

    // ---- gather phase: node = row0 + tid/4, dims [q*16, q*16+16) ----
    {
        int lr = threadIdx.x >> 2;
        int q  = threadIdx.x & 3;
        int gnode = row0 + lr;
        uint4 o0, o1;
        if (gnode < n) {
            const ushort_t* yb = Y + (size_t)gnode * 64 + q * 16;
            uint4 v0 = *(const uint4*)yb;
            uint4 v1 = *(const uint4*)(yb + 8);
            float ga[16];
            ga[0]=bflo(v0.x); ga[1]=bfhi(v0.x); ga[2]=bflo(v0.y); ga[3]=bfhi(v0.y);
            ga[4]=bflo(v0.z); ga[5]=bfhi(v0.z); ga[6]=bflo(v0.w); ga[7]=bfhi(v0.w);
            ga[8]=bflo(v1.x); ga[9]=bfhi(v1.x); ga[10]=bflo(v1.y); ga[11]=bfhi(v1.y);
            ga[12]=bflo(v1.z); ga[13]=bfhi(v1.z); ga[14]=bflo(v1.w); ga[15]=bfhi(v1.w);
            int e = rowptr[gnode], e1 = rowptr[gnode + 1];
            while (e + 1 < e1) {
                const ushort_t* p0 = Y + (size_t)col[e] * 64 + q * 16;
                const ushort_t* p1 = Y + (size_t)col[e + 1] * 64 + q * 16;
                uint4 a0 = *(const uint4*)p0, a1 = *(const uint4*)(p0 + 8);
                uint4 c0 = *(const uint4*)p1, c1 = *(const uint4*)(p1 + 8);
                ga[0]+=bflo(a0.x)+bflo(c0.x); ga[1]+=bfhi(a0.x)+bfhi(c0.x);
                ga[2]+=bflo(a0.y)+bflo(c0.y); ga[3]+=bfhi(a0.y)+bfhi(c0.y);
                ga[4]+=bflo(a0.z)+bflo(c0.z); ga[5]+=bfhi(a0.z)+bfhi(c0.z);
                ga[6]+=bflo(a0.w)+bflo(c0.w); ga[7]+=bfhi(a0.w)+bfhi(c0.w);
                ga[8]+=bflo(a1.x)+bflo(c1.x); ga[9]+=bfhi(a1.x)+bfhi(c1.x);
                ga[10]+=bflo(a1.y)+bflo(c1.y); ga[11]+=bfhi(a1.y)+bfhi(c1.y);
                ga[12]+=bflo(a1.z)+bflo(c1.z); ga[13]+=bfhi(a1.z)+bfhi(c1.z);
                ga[14]+=bflo(a1.w)+bflo(c1.w); ga[15]+=bfhi(a1.w)+bfhi(c1.w);
                e += 2;
            }
            if (e < e1) {
                const ushort_t* p0 = Y + (size_t)col[e] * 64 + q * 16;
                uint4 a0 = *(const uint4*)p0, a1 = *(const uint4*)(p0 + 8);
                ga[0]+=bflo(a0.x); ga[1]+=bfhi(a0.x); ga[2]+=bflo(a0.y); ga[3]+=bfhi(a0.y);
                ga[4]+=bflo(a0.z); ga[5]+=bfhi(a0.z); ga[6]+=bflo(a0.w); ga[7]+=bfhi(a0.w);
                ga[8]+=bflo(a1.x); ga[9]+=bfhi(a1.x); ga[10]+=bflo(a1.y); ga[11]+=bfhi(a1.y);
                ga[12]+=bflo(a1.z); ga[13]+=bfhi(a1.z); ga[14]+=bflo(a1.w); ga[15]+=bfhi(a1.w);
            }
            int d0 = q * 16;
#pragma unroll
            for (int j = 0; j < 16; j++) ga[j] = fmaxf(ga[j] + b1s[d0 + j], 0.0f);
            o0.x = pk(ga[0], ga[1]);  o0.y = pk(ga[2], ga[3]);
            o0.z = pk(ga[4], ga[5]);  o0.w = pk(ga[6], ga[7]);
            o1.x = pk(ga[8], ga[9]);  o1.y = pk(ga[10], ga[11]);
            o1.z = pk(ga[12], ga[13]); o1.w = pk(ga[14], ga[15]);
        } else {
            o0 = make_uint4(0, 0, 0, 0); o1 = o0;
        }
        *(uint4*)&st[lr][q * 16] = o0;
        *(uint4*)&st[lr][q * 16 + 8] = o1;
    }
    __syncthreads();

    // ---- GEMM1: acc = st @ W2 ----
    int w = threadIdx.x >> 6, lane = threadIdx.x & 63;
    int k0base = (lane >> 4) << 3;
    f32x4 acc[4] = {{0,0,0,0},{0,0,0,0},{0,0,0,0},{0,0,0,0}};
#pragma unroll
    for (int ks = 0; ks < 2; ks++) {
        short8 af = *(const short8*)&st[w * 16 + (lane & 15)][ks * 32 + k0base];
#pragma unroll
        for (int ct = 0; ct < 4; ct++) {
            short8 bf = *(const short8*)&w2f[ks][ct][lane][0];
            acc[ct] = __builtin_amdgcn_mfma_f32_16x16x32_bf16(af, bf, acc[ct], 0, 0, 0);
        }
    }
    __syncthreads();

    int colb = lane & 15;
    if (HASNEXT) {
#pragma unroll
        for (int ct = 0; ct < 4; ct++)
#pragma unroll
            for (int r = 0; r < 4; r++) {
                float v = fmaxf(acc[ct][r] + b2s[ct * 16 + colb], 0.0f);
                st[w * 16 + ((lane >> 4) << 2) + r][ct * 16 + colb] = f2bf(v);
            }
        __syncthreads();
        f32x4 acc2[4] = {{0,0,0,0},{0,0,0,0},{0,0,0,0},{0,0,0,0}};
#pragma unroll
        for (int ks = 0; ks < 2; ks++) {
            short8 af2 = *(const short8*)&st[w * 16 + (lane & 15)][ks * 32 + k0base];
#pragma unroll
            for (int ct = 0; ct < 4; ct++) {
                short8 bf = *(const short8*)&wnf[ks][ct][lane][0];
                acc2[ct] = __builtin_amdgcn_mfma_f32_16x16x32_bf16(af2, bf, acc2[ct], 0, 0, 0);
            }
        }
        __syncthreads();
#pragma unroll
        for (int ct = 0; ct < 4; ct++)
#pragma unroll
            for (int r = 0; r < 4; r++)
                st[w * 16 + ((lane >> 4) << 2) + r][ct * 16 + colb] = f2bf(acc2[ct][r]);
        __syncthreads();
        int row = threadIdx.x >> 2, seg = threadIdx.x & 3;
        if (row0 + row < n) {
            const uint4* p = (const uint4*)&st[row][seg * 16];
            uint4 v0 = p[0], v1 = p[1];
            uint4* qp = (uint4*)(Yn + (size_t)(row0 + row) * 64 + seg * 16);
            qp[0] = v0; qp[1] = v1;
        }
    } else {
        // pool reduce (sorted batch)
#pragma unroll
        for (int ct = 0; ct < 4; ct++)
#pragma unroll
            for (int r = 0; r < 4; r++) {
                float v = fmaxf(acc[ct][r] + b2s[ct * 16 + colb], 0.0f);
                vbuf[w * 16 + ((lane >> 4) << 2) + r][ct * 16 + colb] = v;
            }
        __syncthreads();
        int j  = threadIdx.x & 63;
        int i0 = (threadIdx.x >> 6) * 16;
        int cur = -1; float a = 0.0f;
        for (int i = i0; i < i0 + 16; i++) {
            int row = row0 + i;
            if (row >= n) break;
            int b = batch[row];
            if (b != cur) {
                if (cur >= 0) atomicAdd(&sums[cur * 64 + j], a);
                cur = b; a = 0.0f;
            }
            a += vbuf[i][j];
        }
        if (cur >= 0) atomicAdd(&sums[cur * 64 + j], a);
    }
}

// ============ finalize: uses precomputed cntf ============
__global__ __launch_bounds__(64) void finalize_kernel(const float* __restrict__ sums,
                                                      const float* __restrict__ cntf,
                                                      const float* __restrict__ Wl,
                                                      const float* __restrict__ bl,
                                                      float* __restrict__ out, int G) {
    int g = blockIdx.x;
    int j = threadIdx.x;
    __shared__ float gs[64];
    float v = sums[g * 64 + j] / cntf[g];
    gs[j] = v;
    out[G * 2 + g * 64 + j] = v;
    __syncthreads();
    if (j < 2) {
        float acc = bl[j];
#pragma unroll
        for (int k = 0; k < 64; k++) acc += gs[k] * Wl[k * 2 + j];
        out[g * 2 + j] = acc;
    }
}

extern "C" void kernel_launch(void* const* d_in, const int* in_sizes, int n_in,
                              void* d_out, int out_size, void* d_ws, size_t ws_size,
                              hipStream_t stream) {
    const float* x     = (const float*)d_in[0];
    const int*   ei    = (const int*)d_in[1];
    const int*   batch = (const int*)d_in[2];
    const float* W1_0 = (const float*)d_in[3];
    const float* b1_0 = (const float*)d_in[4];
    const float* W2_0 = (const float*)d_in[5];
    const float* b2_0 = (const float*)d_in[6];
    const float* W1_1 = (const float*)d_in[7];
    const float* b1_1 = (const float*)d_in[8];
    const float* W2_1 = (const float*)d_in[9];
    const float* b2_1 = (const float*)d_in[10];
    const float* W1_2 = (const float*)d_in[11];
    const float* b1_2 = (const float*)d_in[12];
    const float* W2_2 = (const float*)d_in[13];
    const float* b2_2 = (const float*)d_in[14];
    const float* Wl   = (const float*)d_in[15];
    const float* bl   = (const float*)d_in[16];

    const int N = in_sizes[0] / 128;
    const int E = in_sizes[1] / 2;
    const int G = out_size / 66;
    const int* src = ei;
    const int* dst = ei + E;
    float* out = (float*)d_out;

    // ---- workspace layout ----
    ushort_t* Y   = (ushort_t*)d_ws;                    // N*64 bf16
    ushort_t* Y2  = Y + (size_t)N * 64;                 // N*64 bf16 (ping-pong)
    float* sums   = (float*)(Y2 + (size_t)N * 64);      // G*64 f32
    int*   deg    = (int*)(sums + (size_t)G * 64);      // N
    int*   flags  = deg + N;                            // 64
    int*   flags2 = flags + 64;                         // 64
    float* cntf   = (float*)(flags2 + 64);              // G
    int*   rowptr = (int*)(cntf + G);                   // N+1
    int*   col    = rowptr + (N + 1);                   // E
    int*   rank   = col + E;                            // E
    int*   aggr   = rank + E;                           // 64

    // ---- zero sums | deg | flags | flags2 (contiguous) ----
    hipMemsetAsync(sums, 0, ((size_t)G * 64 + N + 128) * sizeof(int), stream);

    const int mblk = (N + 63) / 64;
    const int CE = (E + SUBS - 1) / SUBS;
    const int RB = (N + RANGES - 1) / RANGES;

    // ---- CSR build + first GEMM ----
    gemm_hist<<<HB + mblk, 256, 0, stream>>>(x, W1_0, Y, N, dst, deg, rank, E);
    scan_fill<<<64 + RANGES * SUBS + 1, 256, 0, stream>>>(deg, rowptr, aggr, flags, flags2,
                                                          src, dst, rank, col, batch, cntf,
                                                          N, E, CE, RB, G);

    // ---- layers ----
    gfuse<1><<<mblk, 256, 0, stream>>>(Y, rowptr, col, b1_0, W2_0, b2_0, W1_1, Y2, nullptr, nullptr, N);
    gfuse<1><<<mblk, 256, 0, stream>>>(Y2, rowptr, col, b1_1, W2_1, b2_1, W1_2, Y, nullptr, nullptr, N);
    gfuse<0><<<mblk, 256, 0, stream>>>(Y, rowptr, col, b1_2, W2_2, b2_2, nullptr, nullptr, batch, sums, N);
    // ---- head ----
    finalize_kernel<<<G, 64, 0, stream>>>(sums, cntf, Wl, bl, out, G);
}